// Round 4
// baseline (464.528 us; speedup 1.0000x reference)
//
#include <hip/hip_runtime.h>
#include <stdint.h>

#define NB   2
#define SS   2048
#define HIDN 1024
#define NHEAD 16
#define DKK  64

typedef __attribute__((ext_vector_type(8))) short bf16x8;
typedef __attribute__((ext_vector_type(4))) float f32x4;

__device__ __forceinline__ uint16_t f2bf(float f) {
    uint32_t u = __float_as_uint(f);
    u += 0x7FFF + ((u >> 16) & 1);
    return (uint16_t)(u >> 16);
}
__device__ __forceinline__ float bf2f(uint16_t h) {
    return __uint_as_float(((uint32_t)h) << 16);
}
// pack 8 consecutive fp32 (two float4 loads) * sc  -> 8 bf16 in a uint4
__device__ __forceinline__ uint4 pack8(const float* __restrict__ s, float sc) {
    float4 a = *(const float4*)s;
    float4 b = *(const float4*)(s + 4);
    uint4 r;
    uint16_t* p = (uint16_t*)&r;
    p[0] = f2bf(sc * a.x); p[1] = f2bf(sc * a.y);
    p[2] = f2bf(sc * a.z); p[3] = f2bf(sc * a.w);
    p[4] = f2bf(sc * b.x); p[5] = f2bf(sc * b.y);
    p[6] = f2bf(sc * b.z); p[7] = f2bf(sc * b.w);
    return r;
}

// C[M=4096, N=1024] = A[M,1024] @ W[N=1024,K=1024]^T + bias[n]
// A is fp32 when AF32 (q/k/v inputs) else bf16 (workspace X).  W,bias,rowscale fp32.
// MODE 0: out fp32 [m*1024+n]                (final projection -> d_out)
// MODE 1: out bf16 [b][h][s][d]  head-split  (Q, K)
// MODE 2: out bf16 [b][h][d][s]  head-split+T (V, flash B-operand staging)
// rowscale != nullptr: A row m scaled by (1 + rowscale[m])   (K,V pre-scale)
template<int MODE, bool AF32>
__global__ __launch_bounds__(256, 2)
void gemm_proj(const void* __restrict__ Av, const float* __restrict__ W,
               const float* __restrict__ bias, const float* __restrict__ rowscale,
               void* __restrict__ outv)
{
    __shared__ __align__(16) uint16_t As[128 * 32];
    __shared__ __align__(16) uint16_t Bs[128 * 32];
    __shared__ __align__(16) uint16_t Tr[(MODE == 2) ? 128 * 136 : 8];

    const float*    Af = (const float*)Av;
    const uint16_t* Ah = (const uint16_t*)Av;
    float*    out32 = (float*)outv;
    uint16_t* out16 = (uint16_t*)outv;

    const int t    = threadIdx.x;
    const int w    = t >> 6;
    const int lane = t & 63;
    const int q    = lane >> 4;
    const int lr   = lane & 15;
    const int wr   = (w >> 1) * 64;
    const int wc   = (w & 1) * 64;
    const int m0   = blockIdx.y * 128;
    const int n0   = blockIdx.x * 128;

    f32x4 acc[4][4] = {};

    for (int k0 = 0; k0 < HIDN; k0 += 32) {
#pragma unroll
        for (int p = 0; p < 2; ++p) {
            int idx = p * 256 + t;
            int row = idx >> 2;
            int col = (idx & 3) * 8;
            uint4 va;
            if (AF32) {
                float sc = (MODE != 0 && rowscale != nullptr)
                         ? (1.0f + rowscale[m0 + row]) : 1.0f;
                va = pack8(Af + (size_t)(m0 + row) * HIDN + k0 + col, sc);
            } else {
                va = *(const uint4*)(Ah + (size_t)(m0 + row) * HIDN + k0 + col);
            }
            *(uint4*)&As[row * 32 + col] = va;
            *(uint4*)&Bs[row * 32 + col] =
                pack8(W + (size_t)(n0 + row) * HIDN + k0 + col, 1.0f);
        }
        __syncthreads();

        bf16x8 af[4], bfr[4];
#pragma unroll
        for (int i = 0; i < 4; ++i)
            af[i] = *(const bf16x8*)&As[(wr + i * 16 + lr) * 32 + q * 8];
#pragma unroll
        for (int j = 0; j < 4; ++j)
            bfr[j] = *(const bf16x8*)&Bs[(wc + j * 16 + lr) * 32 + q * 8];
#pragma unroll
        for (int i = 0; i < 4; ++i)
#pragma unroll
            for (int j = 0; j < 4; ++j)
                acc[i][j] = __builtin_amdgcn_mfma_f32_16x16x32_bf16(af[i], bfr[j], acc[i][j], 0, 0, 0);
        __syncthreads();
    }

    if (MODE == 0 || MODE == 1) {
        // C/D layout: col = lane&15, row = (lane>>4)*4 + r   [m89-verified]
#pragma unroll
        for (int i = 0; i < 4; ++i) {
            int gmb = m0 + wr + i * 16 + q * 4;
#pragma unroll
            for (int j = 0; j < 4; ++j) {
                int gn = n0 + wc + j * 16 + lr;
                float bv = bias[gn];
#pragma unroll
                for (int r = 0; r < 4; ++r) {
                    float val = acc[i][j][r] + bv;
                    int row = gmb + r;
                    if (MODE == 0) {
                        out32[(size_t)row * HIDN + gn] = val;       // fp32 final out
                    } else {
                        int b = row >> 11, s = row & 2047;
                        size_t dst = (size_t)b * (NHEAD * SS * DKK)
                                   + (size_t)(gn >> 6) * (SS * DKK)
                                   + (size_t)s * DKK + (gn & 63);
                        out16[dst] = f2bf(val);
                    }
                }
            }
        }
    } else {
        // MODE 2: transpose tile in LDS, then coalesced 16B writes of Vt[b][h][d][s]
#pragma unroll
        for (int i = 0; i < 4; ++i) {
            int lrow = wr + i * 16 + q * 4;      // s within tile
#pragma unroll
            for (int j = 0; j < 4; ++j) {
                int lcol = wc + j * 16 + lr;     // d within tile
                float bv = bias[n0 + lcol];
#pragma unroll
                for (int r = 0; r < 4; ++r)
                    Tr[lcol * 136 + lrow + r] = f2bf(acc[i][j][r] + bv);
            }
        }
        __syncthreads();
        int b = m0 >> 11;
#pragma unroll
        for (int p = 0; p < 8; ++p) {
            int idx = p * 256 + t;
            int d   = idx >> 4;
            int sc  = (idx & 15) * 8;
            uint4 v = *(const uint4*)&Tr[d * 136 + sc];
            int h  = (n0 + d) >> 6;
            int dk = (n0 + d) & 63;
            size_t dst = ((size_t)((b * NHEAD + h) * DKK + dk)) * SS + (m0 & 2047) + sc;
            *(uint4*)&out16[dst] = v;
        }
    }
}

// Flash attention: grid (S/128, B*NH). Block = 256 thr = 4 waves; wave owns 32 q-rows.
// Q,K: [B,NH,S,64] bf16; Vt: [B,NH,64,S] bf16; X out bf16: [B,S,1024]
__global__ __launch_bounds__(256, 2)
void flash_attn(const uint16_t* __restrict__ Qg, const uint16_t* __restrict__ Kg,
                const uint16_t* __restrict__ Vtg, const int* __restrict__ mask,
                uint16_t* __restrict__ X)
{
    __shared__ __align__(16) uint16_t Qs[128 * 72];
    __shared__ __align__(16) uint16_t Ks[64 * 72];
    __shared__ __align__(16) uint16_t Vs[64 * 72];        // Vt tile [d][key]
    __shared__ __align__(16) uint16_t Ps[4][32 * 72];     // per-wave P [row][key]
    __shared__ __align__(16) int Msk[SS];

    const int t    = threadIdx.x;
    const int w    = t >> 6;
    const int lane = t & 63;
    const int q    = lane >> 4;
    const int lr   = lane & 15;
    const int qt   = blockIdx.x;
    const int bh   = blockIdx.y;
    const int b    = bh >> 4;
    const int h    = bh & 15;
    const int q0   = qt * 128;
    const size_t headQK = (size_t)bh * SS * DKK;
    const size_t headV  = (size_t)bh * DKK * SS;

#pragma unroll
    for (int p = 0; p < 4; ++p) {
        int idx = p * 256 + t;
        int row = idx >> 3;
        int col = (idx & 7) * 8;
        *(uint4*)&Qs[row * 72 + col] =
            *(const uint4*)(Qg + headQK + (size_t)(q0 + row) * DKK + col);
    }
    {
        const int4* mp = (const int4*)(mask + b * SS);
        int4* sp = (int4*)Msk;
        sp[t] = mp[t];
        sp[256 + t] = mp[256 + t];
    }
    __syncthreads();

    // Q fragments: A[m = lane&15][k = quad*8+j], rows w*32 + mi*16 + lr
    bf16x8 qf[2][2];
#pragma unroll
    for (int mi = 0; mi < 2; ++mi)
#pragma unroll
        for (int kk = 0; kk < 2; ++kk)
            qf[mi][kk] = *(const bf16x8*)&Qs[(w * 32 + mi * 16 + lr) * 72 + kk * 32 + q * 8];

    float mstate[2][4], lstate[2][4];
    f32x4 oacc[2][4] = {};
#pragma unroll
    for (int mi = 0; mi < 2; ++mi)
#pragma unroll
        for (int r = 0; r < 4; ++r) { mstate[mi][r] = -1e30f; lstate[mi][r] = 0.0f; }

    for (int kv0 = 0; kv0 < SS; kv0 += 64) {
#pragma unroll
        for (int p = 0; p < 2; ++p) {
            int idx = p * 256 + t;
            int row = idx >> 3;
            int col = (idx & 7) * 8;
            *(uint4*)&Ks[row * 72 + col] =
                *(const uint4*)(Kg + headQK + (size_t)(kv0 + row) * DKK + col);
            *(uint4*)&Vs[row * 72 + col] =
                *(const uint4*)(Vtg + headV + (size_t)row * SS + kv0 + col);
        }
        __syncthreads();

        // S = Q·K^T
        f32x4 sacc[2][4];
#pragma unroll
        for (int ni = 0; ni < 4; ++ni) {
            bf16x8 kf0 = *(const bf16x8*)&Ks[(ni * 16 + lr) * 72 + 0  + q * 8];
            bf16x8 kf1 = *(const bf16x8*)&Ks[(ni * 16 + lr) * 72 + 32 + q * 8];
#pragma unroll
            for (int mi = 0; mi < 2; ++mi) {
                f32x4 z = {0.0f, 0.0f, 0.0f, 0.0f};
                z = __builtin_amdgcn_mfma_f32_16x16x32_bf16(qf[mi][0], kf0, z, 0, 0, 0);
                z = __builtin_amdgcn_mfma_f32_16x16x32_bf16(qf[mi][1], kf1, z, 0, 0, 0);
                sacc[mi][ni] = z;
            }
        }

        int mv[4];
#pragma unroll
        for (int ni = 0; ni < 4; ++ni) mv[ni] = Msk[kv0 + ni * 16 + lr];

        float rmax[2][4];
#pragma unroll
        for (int mi = 0; mi < 2; ++mi)
#pragma unroll
            for (int r = 0; r < 4; ++r) rmax[mi][r] = -1e30f;
#pragma unroll
        for (int ni = 0; ni < 4; ++ni) {
            bool dead = (mv[ni] == 0);
#pragma unroll
            for (int mi = 0; mi < 2; ++mi)
#pragma unroll
                for (int r = 0; r < 4; ++r) {
                    float sv = dead ? -10000.0f : sacc[mi][ni][r] * 0.125f;
                    sacc[mi][ni][r] = sv;
                    rmax[mi][r] = fmaxf(rmax[mi][r], sv);
                }
        }
#pragma unroll
        for (int mi = 0; mi < 2; ++mi)
#pragma unroll
            for (int r = 0; r < 4; ++r) {
                float v = rmax[mi][r];
                v = fmaxf(v, __shfl_xor(v, 1));
                v = fmaxf(v, __shfl_xor(v, 2));
                v = fmaxf(v, __shfl_xor(v, 4));
                v = fmaxf(v, __shfl_xor(v, 8));
                rmax[mi][r] = v;
            }

        float alpha[2][4], rsum[2][4];
#pragma unroll
        for (int mi = 0; mi < 2; ++mi)
#pragma unroll
            for (int r = 0; r < 4; ++r) {
                float mnew = fmaxf(mstate[mi][r], rmax[mi][r]);
                alpha[mi][r] = __expf(mstate[mi][r] - mnew);
                mstate[mi][r] = mnew;
                rsum[mi][r] = 0.0f;
            }

#pragma unroll
        for (int ni = 0; ni < 4; ++ni)
#pragma unroll
            for (int mi = 0; mi < 2; ++mi)
#pragma unroll
                for (int r = 0; r < 4; ++r) {
                    float p = __expf(sacc[mi][ni][r] - mstate[mi][r]);
                    rsum[mi][r] += p;
                    Ps[w][(mi * 16 + q * 4 + r) * 72 + ni * 16 + lr] = f2bf(p);
                }
#pragma unroll
        for (int mi = 0; mi < 2; ++mi)
#pragma unroll
            for (int r = 0; r < 4; ++r) {
                float v = rsum[mi][r];
                v += __shfl_xor(v, 1);
                v += __shfl_xor(v, 2);
                v += __shfl_xor(v, 4);
                v += __shfl_xor(v, 8);
                lstate[mi][r] = lstate[mi][r] * alpha[mi][r] + v;
            }
#pragma unroll
        for (int mi = 0; mi < 2; ++mi)
#pragma unroll
            for (int dj = 0; dj < 4; ++dj)
#pragma unroll
                for (int r = 0; r < 4; ++r)
                    oacc[mi][dj][r] *= alpha[mi][r];

        __syncthreads();

        // O += P·V
#pragma unroll
        for (int ks = 0; ks < 2; ++ks) {
            bf16x8 pf[2];
#pragma unroll
            for (int mi = 0; mi < 2; ++mi)
                pf[mi] = *(const bf16x8*)&Ps[w][(mi * 16 + lr) * 72 + ks * 32 + q * 8];
#pragma unroll
            for (int dj = 0; dj < 4; ++dj) {
                bf16x8 vf = *(const bf16x8*)&Vs[(dj * 16 + lr) * 72 + ks * 32 + q * 8];
#pragma unroll
                for (int mi = 0; mi < 2; ++mi)
                    oacc[mi][dj] = __builtin_amdgcn_mfma_f32_16x16x32_bf16(pf[mi], vf, oacc[mi][dj], 0, 0, 0);
            }
        }
        __syncthreads();
    }

#pragma unroll
    for (int mi = 0; mi < 2; ++mi)
#pragma unroll
        for (int r = 0; r < 4; ++r) {
            float inv = 1.0f / lstate[mi][r];
            int s = q0 + w * 32 + mi * 16 + q * 4 + r;
#pragma unroll
            for (int dj = 0; dj < 4; ++dj)
                X[(size_t)(b * SS + s) * HIDN + h * DKK + dj * 16 + lr] =
                    f2bf(oacc[mi][dj][r] * inv);
        }
}

extern "C" void kernel_launch(void* const* d_in, const int* in_sizes, int n_in,
                              void* d_out, int out_size, void* d_ws, size_t ws_size,
                              hipStream_t stream) {
    const float* query = (const float*)d_in[0];
    const float* key   = (const float*)d_in[1];
    const float* value = (const float*)d_in[2];
    const float* bias  = (const float*)d_in[3];
    const int*   mask  = (const int*)d_in[4];
    const float* wq = (const float*)d_in[5];
    const float* bq = (const float*)d_in[6];
    const float* wk = (const float*)d_in[7];
    const float* bk = (const float*)d_in[8];
    const float* wv = (const float*)d_in[9];
    const float* bv = (const float*)d_in[10];
    const float* wo = (const float*)d_in[11];
    const float* bo = (const float*)d_in[12];

    const size_t TEN = (size_t)NB * SS * HIDN;   // 4,194,304 elements
    uint16_t* Qb  = (uint16_t*)d_ws;
    uint16_t* Kb  = Qb + TEN;
    uint16_t* Vtb = Kb + TEN;
    uint16_t* Xb  = Vtb + TEN;

    dim3 gg(HIDN / 128, (NB * SS) / 128);   // (8, 32)
    dim3 bb(256);

    gemm_proj<1, true ><<<gg, bb, 0, stream>>>(query, wq, bq, nullptr, Qb);
    gemm_proj<1, true ><<<gg, bb, 0, stream>>>(key,   wk, bk, bias,    Kb);
    gemm_proj<2, true ><<<gg, bb, 0, stream>>>(value, wv, bv, bias,    Vtb);
    flash_attn<<<dim3(SS / 128, NB * NHEAD), bb, 0, stream>>>(Qb, Kb, Vtb, mask, Xb);
    gemm_proj<0, false><<<gg, bb, 0, stream>>>(Xb, wo, bo, nullptr, d_out);
}

// Round 5
// 301.538 us; speedup vs baseline: 1.5405x; 1.5405x over previous
//
#include <hip/hip_runtime.h>
#include <stdint.h>

#define NB   2
#define SS   2048
#define HIDN 1024
#define NHEAD 16
#define DKK  64

typedef __attribute__((ext_vector_type(8))) short bf16x8;
typedef __attribute__((ext_vector_type(4))) float f32x4;

__device__ __forceinline__ uint16_t f2bf(float f) {
    uint32_t u = __float_as_uint(f);
    u += 0x7FFF + ((u >> 16) & 1);
    return (uint16_t)(u >> 16);
}
// pack 8 consecutive fp32 * sc -> 8 bf16 (uint4)
__device__ __forceinline__ uint4 pack8(const float* __restrict__ s, float sc) {
    float4 a = *(const float4*)s;
    float4 b = *(const float4*)(s + 4);
    uint4 r;
    uint16_t* p = (uint16_t*)&r;
    p[0] = f2bf(sc * a.x); p[1] = f2bf(sc * a.y);
    p[2] = f2bf(sc * a.z); p[3] = f2bf(sc * a.w);
    p[4] = f2bf(sc * b.x); p[5] = f2bf(sc * b.y);
    p[6] = f2bf(sc * b.z); p[7] = f2bf(sc * b.w);
    return r;
}
// async global->LDS, 16B per lane; LDS dest = wave-uniform base + lane*16
__device__ __forceinline__ void gl_lds16(const uint16_t* g, uint16_t* l) {
    __builtin_amdgcn_global_load_lds((const __attribute__((address_space(1))) void*)g,
                                     (__attribute__((address_space(3))) void*)l,
                                     16, 0, 0);
}

// ---- conversion kernels (HBM-bound, run once) ----
// q/k/v fp32 -> bf16; k,v scaled by (1+bias[row])
__global__ __launch_bounds__(256, 4)
void cvt_inputs(const float* __restrict__ q, const float* __restrict__ k,
                const float* __restrict__ v, const float* __restrict__ bias,
                uint16_t* __restrict__ q16, uint16_t* __restrict__ k16,
                uint16_t* __restrict__ v16)
{
    int i = blockIdx.x * 256 + threadIdx.x;          // 0..524287 (4M/8)
    size_t e = (size_t)i * 8;
    float sc = 1.0f + bias[i >> 7];                  // row = e/1024
    *(uint4*)(q16 + e) = pack8(q + e, 1.0f);
    *(uint4*)(k16 + e) = pack8(k + e, sc);
    *(uint4*)(v16 + e) = pack8(v + e, sc);
}
// 4 weight matrices fp32 -> contiguous bf16 [wq|wk|wv|wo]
__global__ __launch_bounds__(256, 4)
void cvt_w(const float* __restrict__ w0, const float* __restrict__ w1,
           const float* __restrict__ w2, const float* __restrict__ w3,
           uint16_t* __restrict__ o)
{
    int i = blockIdx.x * 256 + threadIdx.x;          // 0..524287; 131072/matrix
    const float* src = (i < 131072) ? w0 : (i < 262144) ? w1 : (i < 393216) ? w2 : w3;
    size_t e = (size_t)(i & 131071) * 8;
    *(uint4*)(o + (size_t)(i >> 17) * 1048576 + e) = pack8(src + e, 1.0f);
}

// ---- GEMM: C[4096,1024] = A[4096,1024] @ W[1024,1024]^T, all bf16 ----
// tile 128x64, BK=64, global_load_lds + xor-swizzled LDS (no padding allowed).
// MODE 0: out fp32 [m][n] (final)    MODE 1: out bf16 [b][h][s][d], *osc
// MODE 2: out bf16 [b][h][d][s] (V^T for flash B-operand)
template<int MODE>
__global__ __launch_bounds__(256, 3)
void gemm_bt(const uint16_t* __restrict__ A, const uint16_t* __restrict__ W,
             const float* __restrict__ bias, float osc, void* __restrict__ outv)
{
    __shared__ __align__(16) uint16_t As[128 * 64];   // lds[r][g] = glb[r][g^(r&7)]
    __shared__ __align__(16) uint16_t Bs[64 * 64];
    __shared__ __align__(16) uint16_t Tr[(MODE == 2) ? 64 * 136 : 8];

    const int t    = threadIdx.x;
    const int w    = t >> 6;
    const int lane = t & 63;
    const int q    = lane >> 4;
    const int lr   = lane & 15;
    const int wr   = (w >> 1) * 64;                  // wave tile 64x32
    const int wc   = (w & 1) * 32;
    const int m0   = blockIdx.y * 128;
    const int n0   = blockIdx.x * 64;
    const int srow = lane >> 3;                      // staging row-in-8
    const int sg   = (lane & 7) ^ srow;              // swizzled src col-group

    f32x4 acc[4][2] = {};

    for (int k0 = 0; k0 < HIDN; k0 += 64) {
#pragma unroll
        for (int c = 0; c < 4; ++c) {                // A rows w*32..w*32+31
            int r = w * 32 + c * 8;
            gl_lds16(A + (size_t)(m0 + r + srow) * HIDN + k0 + sg * 8, &As[r * 64]);
        }
#pragma unroll
        for (int c = 0; c < 2; ++c) {                // B rows w*16..w*16+15
            int r = w * 16 + c * 8;
            gl_lds16(W + (size_t)(n0 + r + srow) * HIDN + k0 + sg * 8, &Bs[r * 64]);
        }
        __syncthreads();

        bf16x8 af[2][4], bfr[2][2];
#pragma unroll
        for (int s = 0; s < 2; ++s) {
#pragma unroll
            for (int i = 0; i < 4; ++i)
                af[s][i] = *(const bf16x8*)&As[(wr + i * 16 + lr) * 64 +
                                              (((s * 4 + q) ^ (lr & 7)) * 8)];
#pragma unroll
            for (int j = 0; j < 2; ++j)
                bfr[s][j] = *(const bf16x8*)&Bs[(wc + j * 16 + lr) * 64 +
                                               (((s * 4 + q) ^ (lr & 7)) * 8)];
        }
#pragma unroll
        for (int s = 0; s < 2; ++s)
#pragma unroll
            for (int i = 0; i < 4; ++i)
#pragma unroll
                for (int j = 0; j < 2; ++j)
                    acc[i][j] = __builtin_amdgcn_mfma_f32_16x16x32_bf16(
                        af[s][i], bfr[s][j], acc[i][j], 0, 0, 0);
        __syncthreads();
    }

    if (MODE == 0) {
        float* out32 = (float*)outv;
#pragma unroll
        for (int i = 0; i < 4; ++i)
#pragma unroll
            for (int j = 0; j < 2; ++j) {
                int gn = n0 + wc + j * 16 + lr;
                float bv = bias[gn];
#pragma unroll
                for (int r = 0; r < 4; ++r) {
                    int row = m0 + wr + i * 16 + q * 4 + r;
                    out32[(size_t)row * HIDN + gn] = acc[i][j][r] + bv;
                }
            }
    } else if (MODE == 1) {
        uint16_t* o = (uint16_t*)outv;
#pragma unroll
        for (int i = 0; i < 4; ++i)
#pragma unroll
            for (int j = 0; j < 2; ++j) {
                int gn = n0 + wc + j * 16 + lr;
                float bv = bias[gn];
#pragma unroll
                for (int r = 0; r < 4; ++r) {
                    int row = m0 + wr + i * 16 + q * 4 + r;
                    int b = row >> 11, s = row & 2047;
                    size_t dst = (size_t)b * (NHEAD * SS * DKK)
                               + (size_t)(gn >> 6) * (SS * DKK)
                               + (size_t)s * DKK + (gn & 63);
                    o[dst] = f2bf((acc[i][j][r] + bv) * osc);
                }
            }
    } else {
        // transpose 128(s) x 64(d) tile via LDS, then coalesced Vt writes
#pragma unroll
        for (int i = 0; i < 4; ++i)
#pragma unroll
            for (int j = 0; j < 2; ++j) {
                int d = wc + j * 16 + lr;            // 0..63
                float bv = bias[n0 + d];
#pragma unroll
                for (int r = 0; r < 4; ++r) {
                    int sl = wr + i * 16 + q * 4 + r;
                    Tr[d * 136 + sl] = f2bf(acc[i][j][r] + bv);
                }
            }
        __syncthreads();
        uint16_t* o = (uint16_t*)outv;
        int b = m0 >> 11, h = n0 >> 6;
#pragma unroll
        for (int p = 0; p < 4; ++p) {
            int idx = p * 256 + t;
            int d   = idx >> 4;
            int sc8 = (idx & 15) * 8;
            size_t dst = ((size_t)(b * NHEAD + h) * DKK + d) * SS + (m0 & 2047) + sc8;
            *(uint4*)&o[dst] = *(const uint4*)&Tr[d * 136 + sc8];
        }
    }
}

// ---- flash attention: 512 thr = 8 waves x 16 q-rows; Ps aliases dead Qs ----
// Q,K: [B,NH,S,64] bf16 (Q pre-scaled by 1/8); Vt: [B,NH,64,S]; X: [B,S,1024] bf16
__global__ __launch_bounds__(512, 4)
void flash_attn(const uint16_t* __restrict__ Qg, const uint16_t* __restrict__ Kg,
                const uint16_t* __restrict__ Vtg, const int* __restrict__ mask,
                uint16_t* __restrict__ X)
{
    __shared__ __align__(16) uint16_t QP[128 * 72];   // Qs, then per-wave Ps
    __shared__ __align__(16) uint16_t Ks[64 * 72];
    __shared__ __align__(16) uint16_t Vs[64 * 72];
    __shared__ __align__(16) int Msk[SS];

    const int t    = threadIdx.x;
    const int w    = t >> 6;                          // 0..7
    const int lane = t & 63;
    const int q    = lane >> 4;
    const int lr   = lane & 15;
    const int bh   = blockIdx.y;
    const int b    = bh >> 4;
    const int h    = bh & 15;
    const int q0   = blockIdx.x * 128;
    const size_t head = (size_t)bh * SS * DKK;        // same extent for QK and Vt

#pragma unroll
    for (int p = 0; p < 2; ++p) {
        int idx = p * 512 + t;
        int row = idx >> 3;
        int col = (idx & 7) * 8;
        *(uint4*)&QP[row * 72 + col] =
            *(const uint4*)(Qg + head + (size_t)(q0 + row) * DKK + col);
    }
    ((int4*)Msk)[t] = ((const int4*)(mask + b * SS))[t];
    __syncthreads();

    bf16x8 qf[2];
#pragma unroll
    for (int s = 0; s < 2; ++s)
        qf[s] = *(const bf16x8*)&QP[(w * 16 + lr) * 72 + s * 32 + q * 8];

    float mst[4], lst[4];
    f32x4 oacc[4] = {};
#pragma unroll
    for (int r = 0; r < 4; ++r) { mst[r] = -1e30f; lst[r] = 0.0f; }

    for (int kv0 = 0; kv0 < SS; kv0 += 64) {
        {
            int row = t >> 3;
            int col = (t & 7) * 8;
            *(uint4*)&Ks[row * 72 + col] =
                *(const uint4*)(Kg + head + (size_t)(kv0 + row) * DKK + col);
            *(uint4*)&Vs[row * 72 + col] =
                *(const uint4*)(Vtg + head + (size_t)row * SS + kv0 + col);
        }
        __syncthreads();

        f32x4 sacc[4];
#pragma unroll
        for (int ni = 0; ni < 4; ++ni) {
            bf16x8 kf0 = *(const bf16x8*)&Ks[(ni * 16 + lr) * 72 + 0  + q * 8];
            bf16x8 kf1 = *(const bf16x8*)&Ks[(ni * 16 + lr) * 72 + 32 + q * 8];
            f32x4 z = {0.0f, 0.0f, 0.0f, 0.0f};
            z = __builtin_amdgcn_mfma_f32_16x16x32_bf16(qf[0], kf0, z, 0, 0, 0);
            z = __builtin_amdgcn_mfma_f32_16x16x32_bf16(qf[1], kf1, z, 0, 0, 0);
            sacc[ni] = z;
        }

        int mv[4];
#pragma unroll
        for (int ni = 0; ni < 4; ++ni) mv[ni] = Msk[kv0 + ni * 16 + lr];

        float rmax[4] = {-1e30f, -1e30f, -1e30f, -1e30f};
#pragma unroll
        for (int ni = 0; ni < 4; ++ni) {
            bool dead = (mv[ni] == 0);
#pragma unroll
            for (int r = 0; r < 4; ++r) {
                float sv = dead ? -10000.0f : sacc[ni][r];   // Q pre-scaled by 1/8
                sacc[ni][r] = sv;
                rmax[r] = fmaxf(rmax[r], sv);
            }
        }
#pragma unroll
        for (int r = 0; r < 4; ++r) {
            float v = rmax[r];
            v = fmaxf(v, __shfl_xor(v, 1));
            v = fmaxf(v, __shfl_xor(v, 2));
            v = fmaxf(v, __shfl_xor(v, 4));
            v = fmaxf(v, __shfl_xor(v, 8));
            rmax[r] = v;
        }

        float alpha[4], rsum[4];
#pragma unroll
        for (int r = 0; r < 4; ++r) {
            float mnew = fmaxf(mst[r], rmax[r]);
            alpha[r] = __expf(mst[r] - mnew);
            mst[r] = mnew;
            rsum[r] = 0.0f;
        }
#pragma unroll
        for (int ni = 0; ni < 4; ++ni)
#pragma unroll
            for (int r = 0; r < 4; ++r) {
                float p = __expf(sacc[ni][r] - mst[r]);
                rsum[r] += p;
                QP[(w * 16 + q * 4 + r) * 72 + ni * 16 + lr] = f2bf(p);
            }
#pragma unroll
        for (int r = 0; r < 4; ++r) {
            float v = rsum[r];
            v += __shfl_xor(v, 1);
            v += __shfl_xor(v, 2);
            v += __shfl_xor(v, 4);
            v += __shfl_xor(v, 8);
            lst[r] = lst[r] * alpha[r] + v;
        }
#pragma unroll
        for (int dj = 0; dj < 4; ++dj)
#pragma unroll
            for (int r = 0; r < 4; ++r)
                oacc[dj][r] *= alpha[r];

        // Ps is per-wave (own QP rows); DS pipe is in-order per wave -> no barrier
#pragma unroll
        for (int ks = 0; ks < 2; ++ks) {
            bf16x8 pf = *(const bf16x8*)&QP[(w * 16 + lr) * 72 + ks * 32 + q * 8];
#pragma unroll
            for (int dj = 0; dj < 4; ++dj) {
                bf16x8 vf = *(const bf16x8*)&Vs[(dj * 16 + lr) * 72 + ks * 32 + q * 8];
                oacc[dj] = __builtin_amdgcn_mfma_f32_16x16x32_bf16(pf, vf, oacc[dj], 0, 0, 0);
            }
        }
        __syncthreads();   // Ks/Vs free for next tile
    }

#pragma unroll
    for (int r = 0; r < 4; ++r) {
        float inv = 1.0f / lst[r];
        int s = q0 + w * 16 + q * 4 + r;
#pragma unroll
        for (int dj = 0; dj < 4; ++dj)
            X[(size_t)(b * SS + s) * HIDN + h * DKK + dj * 16 + lr] =
                f2bf(oacc[dj][r] * inv);
    }
}

extern "C" void kernel_launch(void* const* d_in, const int* in_sizes, int n_in,
                              void* d_out, int out_size, void* d_ws, size_t ws_size,
                              hipStream_t stream) {
    const float* query = (const float*)d_in[0];
    const float* key   = (const float*)d_in[1];
    const float* value = (const float*)d_in[2];
    const float* bias  = (const float*)d_in[3];
    const int*   mask  = (const int*)d_in[4];
    const float* wq = (const float*)d_in[5];
    const float* bq = (const float*)d_in[6];
    const float* wk = (const float*)d_in[7];
    const float* bk = (const float*)d_in[8];
    const float* wv = (const float*)d_in[9];
    const float* bv = (const float*)d_in[10];
    const float* wo = (const float*)d_in[11];
    const float* bo = (const float*)d_in[12];

    const size_t TEN = (size_t)NB * SS * HIDN;       // 4,194,304
    uint16_t* Qin = (uint16_t*)d_ws;                 // 0
    uint16_t* Kin = Qin + TEN;                       // 4M
    uint16_t* Vin = Kin + TEN;                       // 8M
    uint16_t* W16 = Vin + TEN;                       // 12M (4 x 1M: wq,wk,wv,wo)
    uint16_t* Qb  = W16 + 4 * 1048576;               // 16M
    uint16_t* Kb  = Qb + TEN;                        // 20M
    uint16_t* Vtb = Kb + TEN;                        // 24M  (total 56 MB)
    uint16_t* Xb  = Qin;                             // alias: Qin dead after Q-GEMM

    cvt_inputs<<<2048, 256, 0, stream>>>(query, key, value, bias, Qin, Kin, Vin);
    cvt_w<<<2048, 256, 0, stream>>>(wq, wk, wv, wo, W16);

    dim3 gg(HIDN / 64, (NB * SS) / 128);             // (16, 32) = 512 blocks
    gemm_bt<1><<<gg, 256, 0, stream>>>(Qin, W16,               bq, 0.125f, Qb);
    gemm_bt<1><<<gg, 256, 0, stream>>>(Kin, W16 + 1 * 1048576, bk, 1.0f,   Kb);
    gemm_bt<2><<<gg, 256, 0, stream>>>(Vin, W16 + 2 * 1048576, bv, 1.0f,   Vtb);
    flash_attn<<<dim3(SS / 128, NB * NHEAD), 512, 0, stream>>>(Qb, Kb, Vtb, mask, Xb);
    gemm_bt<0><<<gg, 256, 0, stream>>>(Xb, W16 + 3 * 1048576,  bo, 1.0f,   d_out);
}

// Round 7
// 256.524 us; speedup vs baseline: 1.8109x; 1.1755x over previous
//
#include <hip/hip_runtime.h>
#include <stdint.h>

#define NB   2
#define SS   2048
#define HIDN 1024
#define NHEAD 16
#define DKK  64

typedef __attribute__((ext_vector_type(8))) short bf16x8;
typedef __attribute__((ext_vector_type(4))) float f32x4;

__device__ __forceinline__ uint16_t f2bf(float f) {
    uint32_t u = __float_as_uint(f);
    u += 0x7FFF + ((u >> 16) & 1);
    return (uint16_t)(u >> 16);
}
// pack two fp32 -> packed bf16 pair (lo = f0)
__device__ __forceinline__ uint32_t pk2(float f0, float f1) {
    uint32_t u0 = __float_as_uint(f0);
    uint32_t u1 = __float_as_uint(f1);
    u0 += 0x7FFF + ((u0 >> 16) & 1);
    u1 += 0x7FFF + ((u1 >> 16) & 1);
    return (u0 >> 16) | (u1 & 0xFFFF0000u);
}
// pack 8 consecutive fp32 * sc -> 8 bf16 (uint4)
__device__ __forceinline__ uint4 pack8(const float* __restrict__ s, float sc) {
    float4 a = *(const float4*)s;
    float4 b = *(const float4*)(s + 4);
    uint4 r;
    r.x = pk2(sc * a.x, sc * a.y);
    r.y = pk2(sc * a.z, sc * a.w);
    r.z = pk2(sc * b.x, sc * b.y);
    r.w = pk2(sc * b.z, sc * b.w);
    return r;
}
// async global->LDS, 16B/lane; LDS dest = wave-uniform base + lane*16
__device__ __forceinline__ void gl_lds16(const uint16_t* g, uint16_t* l) {
    __builtin_amdgcn_global_load_lds((const __attribute__((address_space(1))) void*)g,
                                     (__attribute__((address_space(3))) void*)l,
                                     16, 0, 0);
}

// ---- single fused conversion dispatch (HBM-bound) ----
__global__ __launch_bounds__(256, 4)
void cvt_all(const float* __restrict__ q, const float* __restrict__ k,
             const float* __restrict__ v, const float* __restrict__ bias,
             const float* __restrict__ w0, const float* __restrict__ w1,
             const float* __restrict__ w2, const float* __restrict__ w3,
             uint16_t* __restrict__ q16, uint16_t* __restrict__ k16,
             uint16_t* __restrict__ v16, uint16_t* __restrict__ w16o)
{
    int i = blockIdx.x * 256 + threadIdx.x;            // 0..1048575
    if (i < 524288) {                                  // q/k/v: 4M elems each
        size_t e = (size_t)i * 8;
        float sc = 1.0f + bias[i >> 7];
        *(uint4*)(q16 + e) = pack8(q + e, 1.0f);
        *(uint4*)(k16 + e) = pack8(k + e, sc);
        *(uint4*)(v16 + e) = pack8(v + e, sc);
    } else {                                           // 4 weight matrices
        int j = i - 524288;
        const float* src = (j < 131072) ? w0 : (j < 262144) ? w1
                         : (j < 393216) ? w2 : w3;
        size_t e = (size_t)(j & 131071) * 8;
        *(uint4*)(w16o + (size_t)(j >> 17) * 1048576 + e) = pack8(src + e, 1.0f);
    }
}

// ================= GEMM mainloop (shared) =================
// C[128,64] tile of A[4096,1024] @ W[1024,1024]^T. BK=64, double-buffered
// global_load_lds, XOR-swizzled LDS (stride 64): lds[r][g] = glb[r][g^(r&7)].
// One barrier per K-iter; prefetch for it+1 issued right after the barrier so
// the vmcnt(0)-before-next-barrier drains loads that flew across compute.
__device__ __forceinline__ void gemm_core(const uint16_t* __restrict__ A,
                                          const uint16_t* __restrict__ W,
                                          uint16_t* __restrict__ As0,
                                          uint16_t* __restrict__ As1,
                                          uint16_t* __restrict__ Bs0,
                                          uint16_t* __restrict__ Bs1,
                                          int m0, int n0,
                                          f32x4 acc[4][2])
{
    const int t    = threadIdx.x;
    const int w    = t >> 6;
    const int lane = t & 63;
    const int q    = lane >> 4;
    const int lr   = lane & 15;
    const int wr   = (w >> 1) * 64;
    const int wc   = (w & 1) * 32;
    const int srow = lane >> 3;
    const int sg   = (lane & 7) ^ srow;

    // preload tile 0 into buffer 0
#pragma unroll
    for (int c = 0; c < 4; ++c) {
        int r = w * 32 + c * 8;
        gl_lds16(A + (size_t)(m0 + r + srow) * HIDN + sg * 8, As0 + r * 64);
    }
#pragma unroll
    for (int c = 0; c < 2; ++c) {
        int r = w * 16 + c * 8;
        gl_lds16(W + (size_t)(n0 + r + srow) * HIDN + sg * 8, Bs0 + r * 64);
    }

    for (int it = 0; it < 16; ++it) {
        uint16_t* Asc = (it & 1) ? As1 : As0;
        uint16_t* Bsc = (it & 1) ? Bs1 : Bs0;
        uint16_t* Asn = (it & 1) ? As0 : As1;
        uint16_t* Bsn = (it & 1) ? Bs0 : Bs1;
        __syncthreads();
        if (it + 1 < 16) {
            int k0 = (it + 1) * 64;
#pragma unroll
            for (int c = 0; c < 4; ++c) {
                int r = w * 32 + c * 8;
                gl_lds16(A + (size_t)(m0 + r + srow) * HIDN + k0 + sg * 8,
                         Asn + r * 64);
            }
#pragma unroll
            for (int c = 0; c < 2; ++c) {
                int r = w * 16 + c * 8;
                gl_lds16(W + (size_t)(n0 + r + srow) * HIDN + k0 + sg * 8,
                         Bsn + r * 64);
            }
        }
        bf16x8 af[2][4], bfr[2][2];
#pragma unroll
        for (int s = 0; s < 2; ++s) {
#pragma unroll
            for (int i = 0; i < 4; ++i)
                af[s][i] = *(const bf16x8*)&Asc[(wr + i * 16 + lr) * 64 +
                                                (((s * 4 + q) ^ (lr & 7)) * 8)];
#pragma unroll
            for (int j = 0; j < 2; ++j)
                bfr[s][j] = *(const bf16x8*)&Bsc[(wc + j * 16 + lr) * 64 +
                                                 (((s * 4 + q) ^ (lr & 7)) * 8)];
        }
#pragma unroll
        for (int s = 0; s < 2; ++s)
#pragma unroll
            for (int i = 0; i < 4; ++i)
#pragma unroll
                for (int j = 0; j < 2; ++j)
                    acc[i][j] = __builtin_amdgcn_mfma_f32_16x16x32_bf16(
                        af[s][i], bfr[s][j], acc[i][j], 0, 0, 0);
    }
}

// fused Q/K/V projections: grid (16, 32, 3)
__global__ __launch_bounds__(256, 3)
void gemm_qkv(const uint16_t* __restrict__ Qin, const uint16_t* __restrict__ Kin,
              const uint16_t* __restrict__ Vin, const uint16_t* __restrict__ W16,
              const float* __restrict__ bq, const float* __restrict__ bk,
              const float* __restrict__ bv,
              uint16_t* __restrict__ Qb, uint16_t* __restrict__ Kb,
              uint16_t* __restrict__ Vtb)
{
    __shared__ __align__(16) uint16_t As[2][128 * 64];
    __shared__ __align__(16) uint16_t Bs[2][64 * 64];

    const int z = blockIdx.z;
    const uint16_t* A    = (z == 0) ? Qin : (z == 1) ? Kin : Vin;
    const uint16_t* W    = W16 + (size_t)z * 1048576;
    const float*    bias = (z == 0) ? bq : (z == 1) ? bk : bv;
    const float     osc  = (z == 0) ? 0.125f : 1.0f;   // fold 1/sqrt(64) into Q

    const int t    = threadIdx.x;
    const int w    = t >> 6;
    const int lane = t & 63;
    const int q    = lane >> 4;
    const int lr   = lane & 15;
    const int wr   = (w >> 1) * 64;
    const int wc   = (w & 1) * 32;
    const int m0   = blockIdx.y * 128;
    const int n0   = blockIdx.x * 64;

    f32x4 acc[4][2] = {};
    gemm_core(A, W, As[0], As[1], Bs[0], Bs[1], m0, n0, acc);

    if (z < 2) {
        // out bf16 [b][h][s][d]; C/D: col=lane&15, row=(lane>>4)*4+r
        uint16_t* o = (z == 0) ? Qb : Kb;
#pragma unroll
        for (int i = 0; i < 4; ++i)
#pragma unroll
            for (int j = 0; j < 2; ++j) {
                int gn = n0 + wc + j * 16 + lr;
                float bvx = bias[gn];
#pragma unroll
                for (int r = 0; r < 4; ++r) {
                    int row = m0 + wr + i * 16 + q * 4 + r;
                    int b = row >> 11, s = row & 2047;
                    size_t dst = (size_t)b * (NHEAD * SS * DKK)
                               + (size_t)(gn >> 6) * (SS * DKK)
                               + (size_t)s * DKK + (gn & 63);
                    o[dst] = f2bf((acc[i][j][r] + bvx) * osc);
                }
            }
    } else {
        // V^T: transpose 128(s) x 64(d) via LDS (reuse As), coalesced writes
        __syncthreads();
        uint16_t* Tr = (uint16_t*)As;                  // 64 x 136
#pragma unroll
        for (int i = 0; i < 4; ++i)
#pragma unroll
            for (int j = 0; j < 2; ++j) {
                int d = wc + j * 16 + lr;
                float bvx = bias[n0 + d];
#pragma unroll
                for (int r = 0; r < 4; ++r) {
                    int sl = wr + i * 16 + q * 4 + r;
                    Tr[d * 136 + sl] = f2bf(acc[i][j][r] + bvx);
                }
            }
        __syncthreads();
        int b = m0 >> 11, h = n0 >> 6;
#pragma unroll
        for (int p = 0; p < 4; ++p) {
            int idx = p * 256 + t;
            int d   = idx >> 4;
            int sc8 = (idx & 15) * 8;
            size_t dst = ((size_t)(b * NHEAD + h) * DKK + d) * SS
                       + (m0 & 2047) + sc8;
            *(uint4*)&Vtb[dst] = *(const uint4*)&Tr[d * 136 + sc8];
        }
    }
}

// final projection: A bf16 (Xb), out fp32 d_out. grid (16, 32)
__global__ __launch_bounds__(256, 3)
void gemm_out(const uint16_t* __restrict__ Xb, const uint16_t* __restrict__ W,
              const float* __restrict__ bias, float* __restrict__ out)
{
    __shared__ __align__(16) uint16_t As[2][128 * 64];
    __shared__ __align__(16) uint16_t Bs[2][64 * 64];

    const int t    = threadIdx.x;
    const int w    = t >> 6;
    const int lane = t & 63;
    const int q    = lane >> 4;
    const int lr   = lane & 15;
    const int wr   = (w >> 1) * 64;
    const int wc   = (w & 1) * 32;
    const int m0   = blockIdx.y * 128;
    const int n0   = blockIdx.x * 64;

    f32x4 acc[4][2] = {};
    gemm_core(Xb, W, As[0], As[1], Bs[0], Bs[1], m0, n0, acc);

#pragma unroll
    for (int i = 0; i < 4; ++i)
#pragma unroll
        for (int j = 0; j < 2; ++j) {
            int gn = n0 + wc + j * 16 + lr;
            float bvx = bias[gn];
#pragma unroll
            for (int r = 0; r < 4; ++r) {
                int row = m0 + wr + i * 16 + q * 4 + r;
                out[(size_t)row * HIDN + gn] = acc[i][j][r] + bvx;
            }
        }
}

// ---- flash attention, S^T formulation ----
// 512 thr = 8 waves x 16 q-rows. Q pre-scaled 1/8. Per-lane: one q-row (lr),
// 16 keys (ni*16 + q*4 + r). P round-trips LDS as b64 writes / b128 reads.
// Q,K: [B,NH,S,64] bf16; Vt: [B,NH,64,S] bf16; X: [B,S,1024] bf16
__global__ __launch_bounds__(512, 4)
void flash_attn(const uint16_t* __restrict__ Qg, const uint16_t* __restrict__ Kg,
                const uint16_t* __restrict__ Vtg, const int* __restrict__ mask,
                uint16_t* __restrict__ X)
{
    __shared__ __align__(16) uint16_t QP[128 * 72];   // Q, then per-wave P rows
    __shared__ __align__(16) uint16_t Ks[64 * 72];
    __shared__ __align__(16) uint16_t Vs[64 * 72];    // V^T tile [d][key]
    __shared__ __align__(16) float Amf[SS];           // additive mask

    const int t    = threadIdx.x;
    const int w    = t >> 6;
    const int lane = t & 63;
    const int q    = lane >> 4;
    const int lr   = lane & 15;
    const int bh   = blockIdx.y;
    const int b    = bh >> 4;
    const int h    = bh & 15;
    const int q0   = blockIdx.x * 128;
    const size_t head = (size_t)bh * SS * DKK;

#pragma unroll
    for (int p = 0; p < 2; ++p) {
        int idx = p * 512 + t;
        int row = idx >> 3;
        int col = (idx & 7) * 8;
        *(uint4*)&QP[row * 72 + col] =
            *(const uint4*)(Qg + head + (size_t)(q0 + row) * DKK + col);
    }
#pragma unroll
    for (int p = 0; p < 4; ++p) {
        int i = p * 512 + t;
        Amf[i] = (mask[b * SS + i] == 0) ? -10000.0f : 0.0f;
    }
    __syncthreads();

    // Q as B-operand: B[k=quad*8+j][n=lane&15] = Q[n][k]
    bf16x8 qf[2];
#pragma unroll
    for (int s = 0; s < 2; ++s)
        qf[s] = *(const bf16x8*)&QP[(w * 16 + lr) * 72 + s * 32 + q * 8];

    float mst = -1e30f, lst = 0.0f;
    f32x4 oacc[4] = {};

    for (int kv0 = 0; kv0 < SS; kv0 += 64) {
        {
            int row = t >> 3;
            int col = (t & 7) * 8;
            *(uint4*)&Ks[row * 72 + col] =
                *(const uint4*)(Kg + head + (size_t)(kv0 + row) * DKK + col);
            *(uint4*)&Vs[row * 72 + col] =
                *(const uint4*)(Vtg + head + (size_t)row * SS + kv0 + col);
        }
        __syncthreads();

        // S^T[key][q] = K · Q^T : A = K rows, B = Q
        f32x4 st[4];
#pragma unroll
        for (int ni = 0; ni < 4; ++ni) {
            bf16x8 kf0 = *(const bf16x8*)&Ks[(ni * 16 + lr) * 72 + 0  + q * 8];
            bf16x8 kf1 = *(const bf16x8*)&Ks[(ni * 16 + lr) * 72 + 32 + q * 8];
            f32x4 z = {0.0f, 0.0f, 0.0f, 0.0f};
            z = __builtin_amdgcn_mfma_f32_16x16x32_bf16(kf0, qf[0], z, 0, 0, 0);
            z = __builtin_amdgcn_mfma_f32_16x16x32_bf16(kf1, qf[1], z, 0, 0, 0);
            st[ni] = z;
        }

        // additive mask + in-lane row max (lane owns 16 keys of q-row lr)
        float rmax = -1e30f;
#pragma unroll
        for (int ni = 0; ni < 4; ++ni) {
            float4 am = *(const float4*)&Amf[kv0 + ni * 16 + q * 4];
            st[ni][0] += am.x; st[ni][1] += am.y;
            st[ni][2] += am.z; st[ni][3] += am.w;
#pragma unroll
            for (int r = 0; r < 4; ++r) rmax = fmaxf(rmax, st[ni][r]);
        }
        rmax = fmaxf(rmax, __shfl_xor(rmax, 16));
        rmax = fmaxf(rmax, __shfl_xor(rmax, 32));

        float mnew  = fmaxf(mst, rmax);
        float alpha = __expf(mst - mnew);
        mst = mnew;

        float rsum = 0.0f;
#pragma unroll
        for (int ni = 0; ni < 4; ++ni) {
            float p0 = __expf(st[ni][0] - mst);
            float p1 = __expf(st[ni][1] - mst);
            float p2 = __expf(st[ni][2] - mst);
            float p3 = __expf(st[ni][3] - mst);
            rsum += (p0 + p1) + (p2 + p3);
            uint2 pw = make_uint2(pk2(p0, p1), pk2(p2, p3));
            *(uint2*)&QP[(w * 16 + lr) * 72 + ni * 16 + q * 4] = pw;
        }
        rsum += __shfl_xor(rsum, 16);
        rsum += __shfl_xor(rsum, 32);
        lst = lst * alpha + rsum;
#pragma unroll
        for (int dj = 0; dj < 4; ++dj) {
            oacc[dj][0] *= alpha; oacc[dj][1] *= alpha;
            oacc[dj][2] *= alpha; oacc[dj][3] *= alpha;
        }

        // O^T[d][q] += V^T · P^T  (wave-private P rows; DS in-order, no barrier)
#pragma unroll
        for (int ks = 0; ks < 2; ++ks) {
            bf16x8 pfB = *(const bf16x8*)&QP[(w * 16 + lr) * 72 + ks * 32 + q * 8];
#pragma unroll
            for (int dj = 0; dj < 4; ++dj) {
                bf16x8 vfA = *(const bf16x8*)&Vs[(dj * 16 + lr) * 72 + ks * 32 + q * 8];
                oacc[dj] = __builtin_amdgcn_mfma_f32_16x16x32_bf16(vfA, pfB, oacc[dj], 0, 0, 0);
            }
        }
        __syncthreads();   // Ks/Vs free for next tile
    }

    // epilogue: O^T lane holds d = dj*16+q*4+r for q-row s = q0+w*16+lr
    {
        float inv = 1.0f / lst;
        int s = q0 + w * 16 + lr;
        uint16_t* xp = X + (size_t)(b * SS + s) * HIDN + h * DKK;
#pragma unroll
        for (int dj = 0; dj < 4; ++dj) {
            uint2 pw = make_uint2(pk2(oacc[dj][0] * inv, oacc[dj][1] * inv),
                                  pk2(oacc[dj][2] * inv, oacc[dj][3] * inv));
            *(uint2*)(xp + dj * 16 + q * 4) = pw;
        }
    }
}

extern "C" void kernel_launch(void* const* d_in, const int* in_sizes, int n_in,
                              void* d_out, int out_size, void* d_ws, size_t ws_size,
                              hipStream_t stream) {
    const float* query = (const float*)d_in[0];
    const float* key   = (const float*)d_in[1];
    const float* value = (const float*)d_in[2];
    const float* bias  = (const float*)d_in[3];
    const int*   mask  = (const int*)d_in[4];
    const float* wq = (const float*)d_in[5];
    const float* bq = (const float*)d_in[6];
    const float* wk = (const float*)d_in[7];
    const float* bk = (const float*)d_in[8];
    const float* wv = (const float*)d_in[9];
    const float* bv = (const float*)d_in[10];
    const float* wo = (const float*)d_in[11];
    const float* bo = (const float*)d_in[12];

    const size_t TEN = (size_t)NB * SS * HIDN;       // 4,194,304
    uint16_t* Qin = (uint16_t*)d_ws;                 // 0
    uint16_t* Kin = Qin + TEN;                       // 4M
    uint16_t* Vin = Kin + TEN;                       // 8M
    uint16_t* W16 = Vin + TEN;                       // 12M (4 x 1M: wq,wk,wv,wo)
    uint16_t* Qb  = W16 + 4 * 1048576;               // 16M
    uint16_t* Kb  = Qb + TEN;                        // 20M
    uint16_t* Vtb = Kb + TEN;                        // 24M (56 MB total)
    uint16_t* Xb  = Qin;                             // Qin dead after gemm_qkv

    cvt_all<<<4096, 256, 0, stream>>>(query, key, value, bias,
                                      wq, wk, wv, wo, Qin, Kin, Vin, W16);
    gemm_qkv<<<dim3(16, 32, 3), 256, 0, stream>>>(Qin, Kin, Vin, W16,
                                                  bq, bk, bv, Qb, Kb, Vtb);
    flash_attn<<<dim3(SS / 128, NB * NHEAD), 512, 0, stream>>>(Qb, Kb, Vtb, mask, Xb);
    gemm_out<<<dim3(16, 32), 256, 0, stream>>>(Xb, W16 + 3 * 1048576, bo, (float*)d_out);
}